// Round 4
// baseline (204.760 us; speedup 1.0000x reference)
//
#include <hip/hip_runtime.h>
#include <cmath>

#define B_ 16384
#define S_ 512
#define P_ 1024
#define K_ 8
#define D_ 64
#define H_ 128
#define BT 4     // batch rows per block; LDS = 512*4*4B = 8 KB -> 8 blocks/CU (wave-capped)

// ---------------- Kernel A: sklproj[s][h] = dot(skl_emd[s,:], U[h,:]) ----------------
__global__ __launch_bounds__(128) void proj_skl_kernel(
    const float* __restrict__ skl_emd, const float* __restrict__ U,
    float* __restrict__ sklproj) {
  __shared__ float row[D_];
  const int s = blockIdx.x, h = threadIdx.x;
  if (h < D_) row[h] = skl_emd[s * D_ + h];
  __syncthreads();
  float acc = 0.f;
#pragma unroll
  for (int d = 0; d < D_; d++) acc += row[d] * U[h * D_ + d];
  sklproj[s * H_ + h] = acc;
}

// ---------------- Kernel B: att[p][k] = softmax_k( sum_h v[h]*tanh(projP[p][h]+sklproj[g[p][k]][h]) )
__global__ __launch_bounds__(128) void att_kernel(
    const float* __restrict__ plm_emd, const float* __restrict__ W,
    const float* __restrict__ vT, const float* __restrict__ sklproj,
    const int* __restrict__ gidx, float* __restrict__ att) {
  __shared__ float prow[D_];
  __shared__ float red[2][K_];
  const int p = blockIdx.x, h = threadIdx.x;
  if (h < D_) prow[h] = plm_emd[p * D_ + h];
  __syncthreads();
  float pp = 0.f;
#pragma unroll
  for (int d = 0; d < D_; d++) pp += prow[d] * W[h * D_ + d];
  const float v = vT[h];
  int g[K_];
#pragma unroll
  for (int k = 0; k < K_; k++) g[k] = gidx[p * K_ + k];
  float partial[K_];
#pragma unroll
  for (int k = 0; k < K_; k++) partial[k] = v * tanhf(pp + sklproj[g[k] * H_ + h]);
#pragma unroll
  for (int off = 32; off >= 1; off >>= 1)
#pragma unroll
    for (int k = 0; k < K_; k++) partial[k] += __shfl_down(partial[k], off, 64);
  const int wave = h >> 6, lane = h & 63;
  if (lane == 0)
#pragma unroll
    for (int k = 0; k < K_; k++) red[wave][k] = partial[k];
  __syncthreads();
  if (h == 0) {
    float s[K_], m = -1e30f;
#pragma unroll
    for (int k = 0; k < K_; k++) { s[k] = red[0][k] + red[1][k]; m = fmaxf(m, s[k]); }
    float denom = 0.f;
#pragma unroll
    for (int k = 0; k < K_; k++) { s[k] = expf(s[k] - m); denom += s[k]; }
    const float inv = 1.f / denom;
#pragma unroll
    for (int k = 0; k < K_; k++) att[p * K_ + k] = s[k] * inv;
  }
}

// ---------------- Kernel C: out[b][p] = mask[b][p] * sum_k skl_pfc[b][g[p][k]] * att[p][k]
// Transposed LDS tile rows_T[s][bb], BT=4 -> one ds_read_b128 per (p,k) gathers skill s
// for all 4 batch rows. 8 KB LDS -> 8 blocks/CU (32 waves, wave-capped); launch_bounds
// (256,8) caps VGPR at 64 so occupancy is not register-limited.
__global__ __launch_bounds__(256, 8) void out_kernel(
    const float* __restrict__ skl_pfc, const float* __restrict__ mask,
    const float* __restrict__ att, const int* __restrict__ gidx,
    float* __restrict__ out) {
  __shared__ __align__(16) float rows_T[S_][BT];  // 512*4*4B = 8 KB
  const int t = threadIdx.x;
  const int b0 = blockIdx.x * BT;

  // stage transposed: s = t, t+256; per s read 4 batch values (coalesced across t per bb)
#pragma unroll
  for (int i = 0; i < S_ / 256; i++) {
    const int s = t + i * 256;
    float4 v;
    v.x = skl_pfc[(size_t)(b0 + 0) * S_ + s];
    v.y = skl_pfc[(size_t)(b0 + 1) * S_ + s];
    v.z = skl_pfc[(size_t)(b0 + 2) * S_ + s];
    v.w = skl_pfc[(size_t)(b0 + 3) * S_ + s];
    *(float4*)&rows_T[s][0] = v;
  }
  __syncthreads();

  for (int j = 0; j < 4; j++) {
    const int p = t + j * 256;
    const float4* ap = (const float4*)(att + p * K_);
    const int4* gp = (const int4*)(gidx + p * K_);
    const float4 a0 = ap[0], a1 = ap[1];
    const int4 g0 = gp[0], g1 = gp[1];
    const float av[K_] = {a0.x, a0.y, a0.z, a0.w, a1.x, a1.y, a1.z, a1.w};
    const int gv[K_] = {g0.x, g0.y, g0.z, g0.w, g1.x, g1.y, g1.z, g1.w};
    // hoist streaming mask loads so they overlap the LDS gathers
    float m[BT];
#pragma unroll
    for (int bb = 0; bb < BT; bb++) m[bb] = mask[(size_t)(b0 + bb) * P_ + p];
    float acc[BT] = {0.f, 0.f, 0.f, 0.f};
#pragma unroll
    for (int k = 0; k < K_; k++) {
      const float4 v = *(const float4*)&rows_T[gv[k]][0];
      const float a = av[k];
      acc[0] += v.x * a; acc[1] += v.y * a; acc[2] += v.z * a; acc[3] += v.w * a;
    }
#pragma unroll
    for (int bb = 0; bb < BT; bb++)
      out[(size_t)(b0 + bb) * P_ + p] = acc[bb] * m[bb];
  }
}

extern "C" void kernel_launch(void* const* d_in, const int* in_sizes, int n_in,
                              void* d_out, int out_size, void* d_ws, size_t ws_size,
                              hipStream_t stream) {
  const float* skl_pfc = (const float*)d_in[0];   // [B, S]
  const float* mask    = (const float*)d_in[1];   // [B, P]
  const float* skl_emd = (const float*)d_in[2];   // [S, D]
  const float* plm_emd = (const float*)d_in[3];   // [P, D]
  const float* W       = (const float*)d_in[4];   // [H, D]
  const float* U       = (const float*)d_in[5];   // [H, D]
  const float* vT      = (const float*)d_in[6];   // [1, H]
  const int*   gidx    = (const int*)d_in[7];     // [P, K]
  float* out = (float*)d_out;                     // [B, P]

  float* sklproj = (float*)d_ws;                  // S*H floats = 256 KB
  float* att     = sklproj + S_ * H_;             // P*K floats = 32 KB

  proj_skl_kernel<<<S_, 128, 0, stream>>>(skl_emd, U, sklproj);
  att_kernel<<<P_, 128, 0, stream>>>(plm_emd, W, vT, sklproj, gidx, att);
  out_kernel<<<B_ / BT, 256, 0, stream>>>(skl_pfc, mask, att, gidx, out);
}

// Round 5
// 178.142 us; speedup vs baseline: 1.1494x; 1.1494x over previous
//
#include <hip/hip_runtime.h>
#include <cmath>

#define B_ 16384
#define S_ 512
#define P_ 1024
#define K_ 8
#define D_ 64
#define H_ 128
#define BT 16    // batch rows per block -> grid 1024 = exactly 4 blocks/CU, one dispatch round
#define PAD 20   // LDS row stride in floats (80 B): 20*g%32 covers all 8 bank groups; 40 KB -> 4 blocks/CU

// ---------------- Kernel A: sklproj[s][h] = dot(skl_emd[s,:], U[h,:]) ----------------
__global__ __launch_bounds__(128) void proj_skl_kernel(
    const float* __restrict__ skl_emd, const float* __restrict__ U,
    float* __restrict__ sklproj) {
  __shared__ float row[D_];
  const int s = blockIdx.x, h = threadIdx.x;
  if (h < D_) row[h] = skl_emd[s * D_ + h];
  __syncthreads();
  float acc = 0.f;
#pragma unroll
  for (int d = 0; d < D_; d++) acc += row[d] * U[h * D_ + d];
  sklproj[s * H_ + h] = acc;
}

// ---------------- Kernel B: att[p][k] = softmax_k( sum_h v[h]*tanh(projP[p][h]+sklproj[g[p][k]][h]) )
__global__ __launch_bounds__(128) void att_kernel(
    const float* __restrict__ plm_emd, const float* __restrict__ W,
    const float* __restrict__ vT, const float* __restrict__ sklproj,
    const int* __restrict__ gidx, float* __restrict__ att) {
  __shared__ float prow[D_];
  __shared__ float red[2][K_];
  const int p = blockIdx.x, h = threadIdx.x;
  if (h < D_) prow[h] = plm_emd[p * D_ + h];
  __syncthreads();
  float pp = 0.f;
#pragma unroll
  for (int d = 0; d < D_; d++) pp += prow[d] * W[h * D_ + d];
  const float v = vT[h];
  int g[K_];
#pragma unroll
  for (int k = 0; k < K_; k++) g[k] = gidx[p * K_ + k];
  float partial[K_];
#pragma unroll
  for (int k = 0; k < K_; k++) partial[k] = v * tanhf(pp + sklproj[g[k] * H_ + h]);
#pragma unroll
  for (int off = 32; off >= 1; off >>= 1)
#pragma unroll
    for (int k = 0; k < K_; k++) partial[k] += __shfl_down(partial[k], off, 64);
  const int wave = h >> 6, lane = h & 63;
  if (lane == 0)
#pragma unroll
    for (int k = 0; k < K_; k++) red[wave][k] = partial[k];
  __syncthreads();
  if (h == 0) {
    float s[K_], m = -1e30f;
#pragma unroll
    for (int k = 0; k < K_; k++) { s[k] = red[0][k] + red[1][k]; m = fmaxf(m, s[k]); }
    float denom = 0.f;
#pragma unroll
    for (int k = 0; k < K_; k++) { s[k] = expf(s[k] - m); denom += s[k]; }
    const float inv = 1.f / denom;
#pragma unroll
    for (int k = 0; k < K_; k++) att[p * K_ + k] = s[k] * inv;
  }
}

// ---------------- Kernel C: out[b][p] = mask[b][p] * sum_k skl_pfc[b][g[p][k]] * att[p][k]
// Transposed LDS tile rows_T[s][bb] with BT=16: one (p,k) gather = 4x ds_read_b128
// covering 16 batch rows. Grid = 1024 blocks = exactly 4/CU, LDS 40 KB = exactly
// 4 resident -> single dispatch round, no tail. gidx hoisted pre-barrier so the
// gather address chain is ready the moment staging completes.
__global__ __launch_bounds__(256, 4) void out_kernel(
    const float* __restrict__ skl_pfc, const float* __restrict__ mask,
    const float* __restrict__ att, const int* __restrict__ gidx,
    float* __restrict__ out) {
  __shared__ __align__(16) float rows_T[S_][PAD];  // 512*20*4 = 40960 B
  const int t = threadIdx.x;
  const int b0 = blockIdx.x * BT;

  // hoist gidx for all 4 p-chunks (address-critical for the gathers)
  int gv[4][K_];
#pragma unroll
  for (int j = 0; j < 4; j++) {
    const int4* gp = (const int4*)(gidx + (size_t)(t + j * 256) * K_);
    const int4 g0 = gp[0], g1 = gp[1];
    gv[j][0] = g0.x; gv[j][1] = g0.y; gv[j][2] = g0.z; gv[j][3] = g0.w;
    gv[j][4] = g1.x; gv[j][5] = g1.y; gv[j][6] = g1.z; gv[j][7] = g1.w;
  }

  // stage transposed: s = t, t+256; per s read 16 batch values (coalesced across t per bb)
#pragma unroll
  for (int i = 0; i < S_ / 256; i++) {
    const int s = t + i * 256;
    float vals[BT];
#pragma unroll
    for (int bb = 0; bb < BT; bb++) vals[bb] = skl_pfc[(size_t)(b0 + bb) * S_ + s];
    float4* wp = (float4*)&rows_T[s][0];
#pragma unroll
    for (int q = 0; q < 4; q++)
      wp[q] = make_float4(vals[4 * q], vals[4 * q + 1], vals[4 * q + 2], vals[4 * q + 3]);
  }
  __syncthreads();

#pragma unroll
  for (int j = 0; j < 4; j++) {
    const int p = t + j * 256;
    const float4* ap = (const float4*)(att + (size_t)p * K_);
    const float4 a0 = ap[0], a1 = ap[1];
    const float av[K_] = {a0.x, a0.y, a0.z, a0.w, a1.x, a1.y, a1.z, a1.w};
    float m[BT];
#pragma unroll
    for (int bb = 0; bb < BT; bb++) m[bb] = mask[(size_t)(b0 + bb) * P_ + p];
    float acc[BT];
#pragma unroll
    for (int bb = 0; bb < BT; bb++) acc[bb] = 0.f;
#pragma unroll
    for (int k = 0; k < K_; k++) {
      const float4* rp = (const float4*)&rows_T[gv[j][k]][0];
      const float4 v0 = rp[0], v1 = rp[1], v2 = rp[2], v3 = rp[3];
      const float a = av[k];
      acc[0]  += v0.x * a; acc[1]  += v0.y * a; acc[2]  += v0.z * a; acc[3]  += v0.w * a;
      acc[4]  += v1.x * a; acc[5]  += v1.y * a; acc[6]  += v1.z * a; acc[7]  += v1.w * a;
      acc[8]  += v2.x * a; acc[9]  += v2.y * a; acc[10] += v2.z * a; acc[11] += v2.w * a;
      acc[12] += v3.x * a; acc[13] += v3.y * a; acc[14] += v3.z * a; acc[15] += v3.w * a;
    }
#pragma unroll
    for (int bb = 0; bb < BT; bb++)
      out[(size_t)(b0 + bb) * P_ + p] = acc[bb] * m[bb];
  }
}

extern "C" void kernel_launch(void* const* d_in, const int* in_sizes, int n_in,
                              void* d_out, int out_size, void* d_ws, size_t ws_size,
                              hipStream_t stream) {
  const float* skl_pfc = (const float*)d_in[0];   // [B, S]
  const float* mask    = (const float*)d_in[1];   // [B, P]
  const float* skl_emd = (const float*)d_in[2];   // [S, D]
  const float* plm_emd = (const float*)d_in[3];   // [P, D]
  const float* W       = (const float*)d_in[4];   // [H, D]
  const float* U       = (const float*)d_in[5];   // [H, D]
  const float* vT      = (const float*)d_in[6];   // [1, H]
  const int*   gidx    = (const int*)d_in[7];     // [P, K]
  float* out = (float*)d_out;                     // [B, P]

  float* sklproj = (float*)d_ws;                  // S*H floats = 256 KB
  float* att     = sklproj + S_ * H_;             // P*K floats = 32 KB

  proj_skl_kernel<<<S_, 128, 0, stream>>>(skl_emd, U, sklproj);
  att_kernel<<<P_, 128, 0, stream>>>(plm_emd, W, vT, sklproj, gidx, att);
  out_kernel<<<B_ / BT, 256, 0, stream>>>(skl_pfc, mask, att, gidx, out);
}